// Round 6
// baseline (705.775 us; speedup 1.0000x reference)
//
#include <hip/hip_runtime.h>
#include <hip/hip_bf16.h>
#include <math.h>

#define NQ 40000
#define NV 52500
#define D 256
#define NHEAD 8
#define HD 32

using bf16x8 = __attribute__((ext_vector_type(8))) short;
using f32x4  = __attribute__((ext_vector_type(4))) float;

#define LDP 36  // padded LDS row stride (shorts): 72 B = 18 banks, conflict-free

__device__ __forceinline__ short f2bf(float f) {
  union { __hip_bfloat16 h; short s; } u;
  u.h = __float2bfloat16(f);
  return u.s;
}
__device__ __forceinline__ unsigned pack2(float lo, float hi) {
  return (unsigned)(unsigned short)f2bf(lo) |
         ((unsigned)(unsigned short)f2bf(hi) << 16);
}

// ---------------------------------------------------- weight transpose->bf16
__global__ __launch_bounds__(256) void k_wt(const float* __restrict__ Wm,
                                            short* __restrict__ WT, int K, int N) {
  int idx = blockIdx.x * 256 + threadIdx.x;
  if (idx >= N * K) return;
  int n = idx / K, k = idx - n * K;
  WT[idx] = f2bf(Wm[(size_t)k * N + n]);
}

__global__ void k_catbias(const float* __restrict__ a, const float* __restrict__ b,
                          float* __restrict__ o) {
  int i = threadIdx.x;
  if (i < 192) o[i] = a[i];
  else if (i < 288) o[i] = b[i - 192];
}

// ---------------------------------------------------------------- LN1 + qp
__global__ __launch_bounds__(256) void k_ln1(const float* __restrict__ qin,
                                             const float* __restrict__ qpos,
                                             const float* __restrict__ g,
                                             const float* __restrict__ b,
                                             float* __restrict__ id_out,
                                             short* __restrict__ qp_out) {
  int wave = threadIdx.x >> 6;
  int lane = threadIdx.x & 63;
  int row  = blockIdx.x * 4 + wave;
  float4 x = ((const float4*)(qin + (size_t)row * D))[lane];
  float s  = x.x + x.y + x.z + x.w;
  float ss = x.x*x.x + x.y*x.y + x.z*x.z + x.w*x.w;
  for (int o = 32; o > 0; o >>= 1) { s += __shfl_down(s, o); ss += __shfl_down(ss, o); }
  s  = __shfl(s, 0);
  ss = __shfl(ss, 0);
  float m   = s * (1.0f / 256.0f);
  float var = ss * (1.0f / 256.0f) - m * m;
  float rs  = rsqrtf(var + 1e-5f);
  float4 gg = ((const float4*)g)[lane];
  float4 bb = ((const float4*)b)[lane];
  float4 qn;
  qn.x = (x.x - m) * rs * gg.x + bb.x;
  qn.y = (x.y - m) * rs * gg.y + bb.y;
  qn.z = (x.z - m) * rs * gg.z + bb.z;
  qn.w = (x.w - m) * rs * gg.w + bb.w;
  ((float4*)(id_out + (size_t)row * D))[lane] = qn;
  float4 p = ((const float4*)(qpos + (size_t)row * D))[lane];
  short4 o;
  o.x = f2bf(qn.x + p.x); o.y = f2bf(qn.y + p.y);
  o.z = f2bf(qn.z + p.z); o.w = f2bf(qn.w + p.w);
  ((short4*)(qp_out + (size_t)row * D))[lane] = o;
}

// ----------------------------------------------------------- LN2 -> bf16 h
__global__ __launch_bounds__(256) void k_ln2(const float* __restrict__ xin,
                                             const float* __restrict__ g,
                                             const float* __restrict__ b,
                                             short* __restrict__ h_out) {
  int wave = threadIdx.x >> 6;
  int lane = threadIdx.x & 63;
  int row  = blockIdx.x * 4 + wave;
  float4 x = ((const float4*)(xin + (size_t)row * D))[lane];
  float s  = x.x + x.y + x.z + x.w;
  float ss = x.x*x.x + x.y*x.y + x.z*x.z + x.w*x.w;
  for (int o = 32; o > 0; o >>= 1) { s += __shfl_down(s, o); ss += __shfl_down(ss, o); }
  s  = __shfl(s, 0);
  ss = __shfl(ss, 0);
  float m   = s * (1.0f / 256.0f);
  float var = ss * (1.0f / 256.0f) - m * m;
  float rs  = rsqrtf(var + 1e-5f);
  float4 gg = ((const float4*)g)[lane];
  float4 bb = ((const float4*)b)[lane];
  short4 o;
  o.x = f2bf((x.x - m) * rs * gg.x + bb.x);
  o.y = f2bf((x.y - m) * rs * gg.y + bb.y);
  o.z = f2bf((x.z - m) * rs * gg.z + bb.z);
  o.w = f2bf((x.w - m) * rs * gg.w + bb.w);
  ((short4*)(h_out + (size_t)row * D))[lane] = o;
}

// --------------------------------------------------------------- MFMA GEMM
// 128x128 tile, BK=32, reg-staged with explicit next-tile register prefetch,
// padded LDS (rows of 36 shorts -> conflict-free ds_read_b128),
// 4 waves x 4x4 frags of 16x16x32.
// EPI: 0 = store f32; 1 = gelu -> bf16; 2 = + R1 + R2 -> f32; 3 = Cf += v;
//      4 = store bf16
template<int EPI, int CVTA, int K>
__global__ __launch_bounds__(256) void k_gemm(const void* __restrict__ Ain,
                                              const short* __restrict__ WT,
                                              const float* __restrict__ bias,
                                              float* __restrict__ Cf,
                                              short* __restrict__ Cb,
                                              const float* __restrict__ R1,
                                              const float* __restrict__ R2,
                                              int M, int N) {
  __shared__ short Al[128 * LDP];
  __shared__ short Bl[128 * LDP];
  const int tid = threadIdx.x;
  const int m0 = blockIdx.x * 128, n0 = blockIdx.y * 128;
  const int w = tid >> 6, l = tid & 63;
  const int wm = (w >> 1) * 64, wn = (w & 1) * 64;
  const int lr = l & 15, lk = (l >> 4) << 3;

  // staging: thread -> row tid>>1, half tid&1 (16 shorts = 2 int4)
  const int srow = tid >> 1, shalf = (tid & 1) << 4;
  const int arow = min(m0 + srow, M - 1);
  const int brow = min(n0 + srow, N - 1);
  const short* aS = (const short*)Ain + (size_t)arow * K + shalf;
  const float* aSf = (const float*)Ain + (size_t)arow * K + shalf;
  const short* bS = WT + (size_t)brow * K + shalf;
  short* aD = &Al[srow * LDP + shalf];
  short* bD = &Bl[srow * LDP + shalf];

  const bf16x8* aFr[4]; const bf16x8* bFr[4];
#pragma unroll
  for (int i = 0; i < 4; ++i) {
    aFr[i] = (const bf16x8*)&Al[(wm + i * 16 + lr) * LDP + lk];
    bFr[i] = (const bf16x8*)&Bl[(wn + i * 16 + lr) * LDP + lk];
  }

  f32x4 acc[4][4];
#pragma unroll
  for (int i = 0; i < 4; ++i)
#pragma unroll
    for (int j = 0; j < 4; ++j) acc[i][j] = (f32x4){0, 0, 0, 0};

  // prologue: load tile 0 into regs
  int4 la0, la1, lb0, lb1;
  if (CVTA) {
    float4 f0 = *(const float4*)(aSf + 0), f1 = *(const float4*)(aSf + 4);
    float4 f2 = *(const float4*)(aSf + 8), f3 = *(const float4*)(aSf + 12);
    la0.x = pack2(f0.x, f0.y); la0.y = pack2(f0.z, f0.w);
    la0.z = pack2(f1.x, f1.y); la0.w = pack2(f1.z, f1.w);
    la1.x = pack2(f2.x, f2.y); la1.y = pack2(f2.z, f2.w);
    la1.z = pack2(f3.x, f3.y); la1.w = pack2(f3.z, f3.w);
  } else {
    la0 = *(const int4*)(aS + 0);
    la1 = *(const int4*)(aS + 8);
  }
  lb0 = *(const int4*)(bS + 0);
  lb1 = *(const int4*)(bS + 8);

#pragma unroll
  for (int k0 = 0; k0 < K; k0 += 32) {
    if (k0) __syncthreads();           // prev tile's readers done
    *(int4*)aD = la0;
    *(int4*)(aD + 8) = la1;
    *(int4*)bD = lb0;
    *(int4*)(bD + 8) = lb1;
    __syncthreads();                   // tile staged

    if (k0 + 32 < K) {                 // prefetch next tile into regs
      if (CVTA) {
        float4 f0 = *(const float4*)(aSf + k0 + 32);
        float4 f1 = *(const float4*)(aSf + k0 + 36);
        float4 f2 = *(const float4*)(aSf + k0 + 40);
        float4 f3 = *(const float4*)(aSf + k0 + 44);
        la0.x = pack2(f0.x, f0.y); la0.y = pack2(f0.z, f0.w);
        la0.z = pack2(f1.x, f1.y); la0.w = pack2(f1.z, f1.w);
        la1.x = pack2(f2.x, f2.y); la1.y = pack2(f2.z, f2.w);
        la1.z = pack2(f3.x, f3.y); la1.w = pack2(f3.z, f3.w);
      } else {
        la0 = *(const int4*)(aS + k0 + 32);
        la1 = *(const int4*)(aS + k0 + 40);
      }
      lb0 = *(const int4*)(bS + k0 + 32);
      lb1 = *(const int4*)(bS + k0 + 40);
    }

    bf16x8 af[4], bf[4];
#pragma unroll
    for (int i = 0; i < 4; ++i) { af[i] = *aFr[i]; bf[i] = *bFr[i]; }
#pragma unroll
    for (int i = 0; i < 4; ++i)
#pragma unroll
      for (int j = 0; j < 4; ++j)
        acc[i][j] = __builtin_amdgcn_mfma_f32_16x16x32_bf16(af[i], bf[j], acc[i][j], 0, 0, 0);
  }

  const int er = (l >> 4) << 2;
  const int ec = l & 15;
#pragma unroll
  for (int i = 0; i < 4; ++i) {
#pragma unroll
    for (int j = 0; j < 4; ++j) {
      int col = n0 + wn + j * 16 + ec;
      if (col >= N) continue;
      float bcol = bias[col];
#pragma unroll
      for (int r = 0; r < 4; ++r) {
        int row = m0 + wm + i * 16 + er + r;
        if (row >= M) continue;
        float v = acc[i][j][r] + bcol;
        size_t off = (size_t)row * N + col;
        if (EPI == 0) {
          Cf[off] = v;
        } else if (EPI == 1) {
          Cb[off] = f2bf(0.5f * v * (1.0f + erff(v * 0.70710678118f)));
        } else if (EPI == 2) {
          Cf[off] = v + R1[off] + R2[off];
        } else if (EPI == 3) {
          Cf[off] += v;
        } else {
          Cb[off] = f2bf(v);
        }
      }
    }
  }
}

// ---------------- softmax + per-point sampling meta: idx0 + 4 bf16 tap wgts
__global__ __launch_bounds__(256) void k_post(const float* __restrict__ res,
                                              const float* __restrict__ refp,
                                              int* __restrict__ idxA,
                                              unsigned short* __restrict__ wA) {
  int t = blockIdx.x * 256 + threadIdx.x;
  if (t >= NQ * 8) return;
  int q = t >> 3, h = t & 7;
  const float* rr = res + (size_t)q * 288;
  const float* lg = rr + 192 + h * 12;
  float mx = lg[0];
#pragma unroll
  for (int i = 1; i < 12; ++i) mx = fmaxf(mx, lg[i]);
  float e[12]; float sum = 0.0f;
#pragma unroll
  for (int i = 0; i < 12; ++i) { e[i] = expf(lg[i] - mx); sum += e[i]; }
  float inv = 1.0f / sum;

  const float dims[3] = {200.0f, 100.0f, 50.0f};
  const int   sts[3]  = {0, 40000, 50000};
#pragma unroll
  for (int l = 0; l < 3; ++l) {
    const int W = (int)dims[l];
    const float fW = dims[l];
    float rx = refp[((size_t)q * 3 + l) * 2 + 0];
    float ry = refp[((size_t)q * 3 + l) * 2 + 1];
    float invd = 1.0f / fW;
#pragma unroll
    for (int p = 0; p < 4; ++p) {
      int j = ((h * 3 + l) * 4 + p) * 2;
      float lx = rx + rr[j + 0] * invd;
      float ly = ry + rr[j + 1] * invd;
      float fx = lx * fW - 0.5f;
      float fy = ly * fW - 0.5f;
      float x0f = floorf(fx), y0f = floorf(fy);
      float tx = fx - x0f, ty = fy - y0f;
      int x0 = (int)x0f, y0 = (int)y0f;
      bool vx0 = (unsigned)x0       < (unsigned)W;
      bool vx1 = (unsigned)(x0 + 1) < (unsigned)W;
      bool vy0 = (unsigned)y0       < (unsigned)W;
      bool vy1 = (unsigned)(y0 + 1) < (unsigned)W;
      float a = e[l * 4 + p] * inv;
      float w00 = (vx0 && vy0) ? a * (1.0f - tx) * (1.0f - ty) : 0.0f;
      float w01 = (vx1 && vy0) ? a * tx * (1.0f - ty) : 0.0f;
      float w10 = (vx0 && vy1) ? a * (1.0f - tx) * ty : 0.0f;
      float w11 = (vx1 && vy1) ? a * tx * ty : 0.0f;
      int pidx = t * 12 + l * 4 + p;
      idxA[pidx] = sts[l] + y0 * W + x0;
      short4 wpk;
      wpk.x = f2bf(w00); wpk.y = f2bf(w01);
      wpk.z = f2bf(w10); wpk.w = f2bf(w11);
      *(short4*)(wA + (size_t)pidx * 4) = wpk;
    }
  }
}

// ----------------------------------------------------------- deform sampling
__global__ __launch_bounds__(256) void k_sample(const short* __restrict__ vproj,
                                                const int* __restrict__ idxA,
                                                const unsigned short* __restrict__ wA,
                                                short* __restrict__ smp) {
  const int lane = threadIdx.x & 63;
  const int qh   = blockIdx.x * 4 + (threadIdx.x >> 6);
  const int h = qh & 7;
  const int pg  = lane >> 4;         // point in level
  const int tap = (lane >> 2) & 3;   // dy,dx
  const int cq  = lane & 3;          // channel oct (8 ch)
  const int dy = tap >> 1, dx = tap & 1;
  const short* vb = vproj + h * HD + cq * 8;

  float acc[8];
#pragma unroll
  for (int j = 0; j < 8; ++j) acc[j] = 0.0f;

  const int Dim[3] = {200, 100, 50};
#pragma unroll
  for (int l = 0; l < 3; ++l) {
    const int W = Dim[l];
    const int tapoff = dy * W + dx;
    int pidx = qh * 12 + l * 4 + pg;
    int idx = idxA[pidx] + tapoff;
    idx = min(max(idx, 0), NV - 1);
    float wgt = __uint_as_float((unsigned)wA[(size_t)pidx * 4 + tap] << 16);
    uint4 v = *(const uint4*)(vb + (size_t)idx * D);
    acc[0] = fmaf(wgt, __uint_as_float(v.x << 16),        acc[0]);
    acc[1] = fmaf(wgt, __uint_as_float(v.x & 0xffff0000u), acc[1]);
    acc[2] = fmaf(wgt, __uint_as_float(v.y << 16),        acc[2]);
    acc[3] = fmaf(wgt, __uint_as_float(v.y & 0xffff0000u), acc[3]);
    acc[4] = fmaf(wgt, __uint_as_float(v.z << 16),        acc[4]);
    acc[5] = fmaf(wgt, __uint_as_float(v.z & 0xffff0000u), acc[5]);
    acc[6] = fmaf(wgt, __uint_as_float(v.w << 16),        acc[6]);
    acc[7] = fmaf(wgt, __uint_as_float(v.w & 0xffff0000u), acc[7]);
  }

#pragma unroll
  for (int off = 4; off <= 32; off <<= 1) {
#pragma unroll
    for (int j = 0; j < 8; ++j) acc[j] += __shfl_xor(acc[j], off);
  }

  if (lane < 4) {
    uint4 o;
    o.x = pack2(acc[0], acc[1]);
    o.y = pack2(acc[2], acc[3]);
    o.z = pack2(acc[4], acc[5]);
    o.w = pack2(acc[6], acc[7]);
    *(uint4*)(smp + (size_t)qh * HD + cq * 8) = o;
  }
}

// ---------------------------------------------------------------------------
extern "C" void kernel_launch(void* const* d_in, const int* in_sizes, int n_in,
                              void* d_out, int out_size, void* d_ws, size_t ws_size,
                              hipStream_t stream) {
  const float* query  = (const float*)d_in[0];
  const float* value  = (const float*)d_in[1];
  const float* qpos   = (const float*)d_in[2];
  const float* refp   = (const float*)d_in[3];
  const float* n1g = (const float*)d_in[6];
  const float* n1b = (const float*)d_in[7];
  const float* Woff = (const float*)d_in[8];
  const float* boff = (const float*)d_in[9];
  const float* Wattn = (const float*)d_in[10];
  const float* battn = (const float*)d_in[11];
  const float* Wval = (const float*)d_in[12];
  const float* bval = (const float*)d_in[13];
  const float* Wout = (const float*)d_in[14];
  const float* bout = (const float*)d_in[15];
  const float* n2g = (const float*)d_in[16];
  const float* n2b = (const float*)d_in[17];
  const float* W1 = (const float*)d_in[18];
  const float* b1 = (const float*)d_in[19];
  const float* W2 = (const float*)d_in[20];
  const float* b2 = (const float*)d_in[21];

  float* out = (float*)d_out;
  char* Wb = (char*)d_ws;

  // workspace layout (time-overlaid; ~156 MB total)
  short* qp_bf   = (short*)Wb;                    // [0,20.48M)   ln1 -> gemm288
  float* iden    = (float*)(Wb + 20480000);       // [20.48M,61.44M) ln1 -> outproj
  int*   idxA    = (int*)(Wb + 61440000);         // [61.44M,76.8M)  post -> sample
  unsigned short* wA = (unsigned short*)(Wb + 76800000); // [76.8M,107.52M)
  float* res     = (float*)(Wb + 107520000);      // [107.52M,153.6M) gemm288 -> post
  short* vprj_bf = (short*)(Wb + 107520000);      // [107.52M,134.4M) vproj -> sample
  short* h_bf    = (short*)(Wb + 107520000);      // [107.52M,128M)   ln2 -> ffn1
  short* smp_bf  = (short*)(Wb + 134400000);      // [134.4M,154.88M) sample -> outproj
  short* mid_bf  = (short*)Wb;                    // [0,81.92M) ffn1 -> ffn2
  short* WT288   = (short*)(Wb + 154880000);
  short* WTval   = (short*)(Wb + 155027456);
  short* WTout   = (short*)(Wb + 155158528);
  short* WT1     = (short*)(Wb + 155289600);
  short* WT2     = (short*)(Wb + 155813888);
  float* bias288 = (float*)(Wb + 156338176);

  // weight prep
  k_wt<<<(192 * 256 + 255) / 256, 256, 0, stream>>>(Woff, WT288, 256, 192);
  k_wt<<<(96 * 256 + 255) / 256, 256, 0, stream>>>(Wattn, WT288 + 192 * 256, 256, 96);
  k_wt<<<(256 * 256 + 255) / 256, 256, 0, stream>>>(Wval, WTval, 256, 256);
  k_wt<<<(256 * 256 + 255) / 256, 256, 0, stream>>>(Wout, WTout, 256, 256);
  k_wt<<<(1024 * 256 + 255) / 256, 256, 0, stream>>>(W1, WT1, 256, 1024);
  k_wt<<<(256 * 1024 + 255) / 256, 256, 0, stream>>>(W2, WT2, 1024, 256);
  k_catbias<<<1, 320, 0, stream>>>(boff, battn, bias288);

  // LN1 -> iden(f32), qp(bf16)
  k_ln1<<<NQ / 4, 256, 0, stream>>>(query, qpos, n1g, n1b, iden, qp_bf);

  // offsets+attn logits GEMM (N=288)
  k_gemm<0,0,256><<<dim3((NQ + 127) / 128, 3), 256, 0, stream>>>(
      qp_bf, WT288, bias288, res, nullptr, nullptr, nullptr, NQ, 288);
  // softmax + sampling meta
  k_post<<<(NQ * 8 + 255) / 256, 256, 0, stream>>>(res, refp, idxA, wA);

  // value proj (fused f32->bf16 A staging) -> bf16
  k_gemm<4,1,256><<<dim3((NV + 127) / 128, 2), 256, 0, stream>>>(
      value, WTval, bval, nullptr, vprj_bf, nullptr, nullptr, NV, 256);

  // deformable sampling -> smp(bf16)
  k_sample<<<NQ * NHEAD / 4, 256, 0, stream>>>(vprj_bf, idxA, wA, smp_bf);

  // out proj + residuals -> x (d_out)
  k_gemm<2,0,256><<<dim3((NQ + 127) / 128, 2), 256, 0, stream>>>(
      smp_bf, WTout, bout, out, nullptr, query, iden, NQ, 256);

  // LN2 -> h(bf16)
  k_ln2<<<NQ / 4, 256, 0, stream>>>(out, n2g, n2b, h_bf);

  // FFN1: gelu(h@W1+b1) -> mid(bf16)
  k_gemm<1,0,256><<<dim3((NQ + 127) / 128, 8), 256, 0, stream>>>(
      h_bf, WT1, b1, nullptr, mid_bf, nullptr, nullptr, NQ, 1024);

  // FFN2: x += mid@W2+b2 (in place on d_out)
  k_gemm<3,0,1024><<<dim3((NQ + 127) / 128, 2), 256, 0, stream>>>(
      mid_bf, WT2, b2, out, nullptr, nullptr, nullptr, NQ, 256);
}

// Round 7
// 481.300 us; speedup vs baseline: 1.4664x; 1.4664x over previous
//
#include <hip/hip_runtime.h>
#include <hip/hip_bf16.h>
#include <math.h>

#define NQ 40000
#define NV 52500
#define D 256
#define NHEAD 8
#define HD 32

using bf16x8 = __attribute__((ext_vector_type(8))) short;
using f32x4  = __attribute__((ext_vector_type(4))) float;

__device__ __forceinline__ short f2bf(float f) {
  union { __hip_bfloat16 h; short s; } u;
  u.h = __float2bfloat16(f);
  return u.s;
}
__device__ __forceinline__ unsigned pack2(float lo, float hi) {
  return (unsigned)(unsigned short)f2bf(lo) |
         ((unsigned)(unsigned short)f2bf(hi) << 16);
}
// async global->LDS, 16B per lane, wave-uniform LDS base
__device__ __forceinline__ void gload16(const void* g, void* l) {
  __builtin_amdgcn_global_load_lds(
      (const __attribute__((address_space(1))) unsigned int*)g,
      (__attribute__((address_space(3))) unsigned int*)l, 16, 0, 0);
}

// ---------------------------------------------------- weight transpose->bf16
__global__ __launch_bounds__(256) void k_wt(const float* __restrict__ Wm,
                                            short* __restrict__ WT, int K, int N) {
  int idx = blockIdx.x * 256 + threadIdx.x;
  if (idx >= N * K) return;
  int n = idx / K, k = idx - n * K;
  WT[idx] = f2bf(Wm[(size_t)k * N + n]);
}

__global__ void k_catbias(const float* __restrict__ a, const float* __restrict__ b,
                          float* __restrict__ o) {
  int i = threadIdx.x;
  if (i < 192) o[i] = a[i];
  else if (i < 288) o[i] = b[i - 192];
}

// ---------------------------------------------------------------- LN1 + qp
__global__ __launch_bounds__(256) void k_ln1(const float* __restrict__ qin,
                                             const float* __restrict__ qpos,
                                             const float* __restrict__ g,
                                             const float* __restrict__ b,
                                             float* __restrict__ id_out,
                                             short* __restrict__ qp_out) {
  int wave = threadIdx.x >> 6;
  int lane = threadIdx.x & 63;
  int row  = blockIdx.x * 4 + wave;
  float4 x = ((const float4*)(qin + (size_t)row * D))[lane];
  float s  = x.x + x.y + x.z + x.w;
  float ss = x.x*x.x + x.y*x.y + x.z*x.z + x.w*x.w;
  for (int o = 32; o > 0; o >>= 1) { s += __shfl_down(s, o); ss += __shfl_down(ss, o); }
  s  = __shfl(s, 0);
  ss = __shfl(ss, 0);
  float m   = s * (1.0f / 256.0f);
  float var = ss * (1.0f / 256.0f) - m * m;
  float rs  = rsqrtf(var + 1e-5f);
  float4 gg = ((const float4*)g)[lane];
  float4 bb = ((const float4*)b)[lane];
  float4 qn;
  qn.x = (x.x - m) * rs * gg.x + bb.x;
  qn.y = (x.y - m) * rs * gg.y + bb.y;
  qn.z = (x.z - m) * rs * gg.z + bb.z;
  qn.w = (x.w - m) * rs * gg.w + bb.w;
  ((float4*)(id_out + (size_t)row * D))[lane] = qn;
  float4 p = ((const float4*)(qpos + (size_t)row * D))[lane];
  short4 o;
  o.x = f2bf(qn.x + p.x); o.y = f2bf(qn.y + p.y);
  o.z = f2bf(qn.z + p.z); o.w = f2bf(qn.w + p.w);
  ((short4*)(qp_out + (size_t)row * D))[lane] = o;
}

// ----------------------------------------------------------- LN2 -> bf16 h
__global__ __launch_bounds__(256) void k_ln2(const float* __restrict__ xin,
                                             const float* __restrict__ g,
                                             const float* __restrict__ b,
                                             short* __restrict__ h_out) {
  int wave = threadIdx.x >> 6;
  int lane = threadIdx.x & 63;
  int row  = blockIdx.x * 4 + wave;
  float4 x = ((const float4*)(xin + (size_t)row * D))[lane];
  float s  = x.x + x.y + x.z + x.w;
  float ss = x.x*x.x + x.y*x.y + x.z*x.z + x.w*x.w;
  for (int o = 32; o > 0; o >>= 1) { s += __shfl_down(s, o); ss += __shfl_down(ss, o); }
  s  = __shfl(s, 0);
  ss = __shfl(ss, 0);
  float m   = s * (1.0f / 256.0f);
  float var = ss * (1.0f / 256.0f) - m * m;
  float rs  = rsqrtf(var + 1e-5f);
  float4 gg = ((const float4*)g)[lane];
  float4 bb = ((const float4*)b)[lane];
  short4 o;
  o.x = f2bf((x.x - m) * rs * gg.x + bb.x);
  o.y = f2bf((x.y - m) * rs * gg.y + bb.y);
  o.z = f2bf((x.z - m) * rs * gg.z + bb.z);
  o.w = f2bf((x.w - m) * rs * gg.w + bb.w);
  ((short4*)(h_out + (size_t)row * D))[lane] = o;
}

// --------------------------------------------------------------- MFMA GEMM
// 128x128 tile, BK=32, double-buffered LDS, 2-phase pipeline:
//   stage(t+1 -> buf^1) issued BEFORE compute(t on buf); one barrier/iter.
// LDS linear [128][32] shorts; bank conflicts broken by XOR slot swizzle
// (slot ^= (row>>1)&3, 16B slots) applied to the GLOBAL source address and
// the ds_read address (LDS dest of global_load_lds stays linear).
// EPI: 0 = store f32; 1 = gelu -> bf16; 2 = + R1 + R2 -> f32; 3 = Cf += v;
//      4 = store bf16
template<int EPI, int CVTA, int K>
__global__ __launch_bounds__(256) void k_gemm(const void* __restrict__ Ain,
                                              const short* __restrict__ WT,
                                              const float* __restrict__ bias,
                                              float* __restrict__ Cf,
                                              short* __restrict__ Cb,
                                              const float* __restrict__ R1,
                                              const float* __restrict__ R2,
                                              int M, int N) {
  constexpr int NT = K / 32;
  __shared__ short Al[2][4096];
  __shared__ short Bl[2][4096];
  const int tid = threadIdx.x;
  const int n0 = blockIdx.x * 128, m0 = blockIdx.y * 128;   // x = N tiles!
  const int w = tid >> 6, l = tid & 63;
  const int wm = (w >> 1) * 64, wn = (w & 1) * 64;
  const int lr = l & 15;

  // staging: chunk c (= w*2 + {0,1}) covers tile rows [16c, 16c+16).
  // lane covers row 16c + (l>>2), LDS 16B-slot (l&3) (linear dest).
  // source slot is swizzled: (l&3) ^ f(row), f(row) = (row>>1)&3 = (l>>3)&3.
  const int c0 = w * 2, c1 = c0 + 1;
  const int sr = l >> 2;
  const int sg = (((l & 3) ^ ((l >> 3) & 3)) << 3);   // shorts offset in row
  const int ar0 = min(m0 + c0 * 16 + sr, M - 1);
  const int ar1 = min(m0 + c1 * 16 + sr, M - 1);
  const int br0 = min(n0 + c0 * 16 + sr, N - 1);
  const int br1 = min(n0 + c1 * 16 + sr, N - 1);
  const short* bP0 = WT + (size_t)br0 * K + sg;
  const short* bP1 = WT + (size_t)br1 * K + sg;
  const short* aP0 = (const short*)Ain + (size_t)ar0 * K + sg;
  const short* aP1 = (const short*)Ain + (size_t)ar1 * K + sg;
  const float* aF0 = (const float*)Ain + (size_t)ar0 * K + sg;
  const float* aF1 = (const float*)Ain + (size_t)ar1 * K + sg;
  // CVTA ds_write dests (per-lane, linear slot); + buf*4096 shorts for buf 1
  short* wD0 = &Al[0][(c0 * 16 + sr) * 32 + ((l & 3) << 3)];
  short* wD1 = &Al[0][(c1 * 16 + sr) * 32 + ((l & 3) << 3)];

  // fragment read offsets (shorts): row (wm|wn)+i*16+lr, want k-slot (l>>4),
  // actual LDS slot = (l>>4) ^ f(row) with f(row) = ((l&15)>>1)&3.
  const int fsw = (((l >> 4) ^ ((l >> 1) & 3)) << 3);
  const int aRd = (wm + lr) * 32 + fsw;
  const int bRd = (wn + lr) * 32 + fsw;

  f32x4 acc[4][4];
#pragma unroll
  for (int i = 0; i < 4; ++i)
#pragma unroll
    for (int j = 0; j < 4; ++j) acc[i][j] = (f32x4){0, 0, 0, 0};

  // ---- prologue: stage tile 0 into buf 0
  if (CVTA) {
    float4 f00 = *(const float4*)(aF0);
    float4 f01 = *(const float4*)(aF0 + 4);
    float4 f10 = *(const float4*)(aF1);
    float4 f11 = *(const float4*)(aF1 + 4);
    int4 p0, p1;
    p0.x = pack2(f00.x, f00.y); p0.y = pack2(f00.z, f00.w);
    p0.z = pack2(f01.x, f01.y); p0.w = pack2(f01.z, f01.w);
    p1.x = pack2(f10.x, f10.y); p1.y = pack2(f10.z, f10.w);
    p1.z = pack2(f11.x, f11.y); p1.w = pack2(f11.z, f11.w);
    *(int4*)wD0 = p0;
    *(int4*)wD1 = p1;
  } else {
    gload16(aP0, &Al[0][c0 * 512]);
    gload16(aP1, &Al[0][c1 * 512]);
  }
  gload16(bP0, &Bl[0][c0 * 512]);
  gload16(bP1, &Bl[0][c1 * 512]);
  __syncthreads();

#pragma unroll 2
  for (int t = 0; t < NT - 1; ++t) {
    const int buf = t & 1, nbuf = buf ^ 1;
    const int kn = (t + 1) * 32;
    // issue stage of tile t+1 into buf^1 (drained at this iter's barrier)
    float4 f00, f01, f10, f11;
    if (CVTA) {
      f00 = *(const float4*)(aF0 + kn);
      f01 = *(const float4*)(aF0 + kn + 4);
      f10 = *(const float4*)(aF1 + kn);
      f11 = *(const float4*)(aF1 + kn + 4);
    } else {
      gload16(aP0 + kn, &Al[nbuf][c0 * 512]);
      gload16(aP1 + kn, &Al[nbuf][c1 * 512]);
    }
    gload16(bP0 + kn, &Bl[nbuf][c0 * 512]);
    gload16(bP1 + kn, &Bl[nbuf][c1 * 512]);

    // compute on buf
    bf16x8 af[4], bfr[4];
#pragma unroll
    for (int i = 0; i < 4; ++i) {
      af[i]  = *(const bf16x8*)&Al[buf][aRd + i * 512];
      bfr[i] = *(const bf16x8*)&Bl[buf][bRd + i * 512];
    }
#pragma unroll
    for (int i = 0; i < 4; ++i)
#pragma unroll
      for (int j = 0; j < 4; ++j)
        acc[i][j] = __builtin_amdgcn_mfma_f32_16x16x32_bf16(af[i], bfr[j], acc[i][j], 0, 0, 0);

    if (CVTA) {  // write-late half of the A staging
      int4 p0, p1;
      p0.x = pack2(f00.x, f00.y); p0.y = pack2(f00.z, f00.w);
      p0.z = pack2(f01.x, f01.y); p0.w = pack2(f01.z, f01.w);
      p1.x = pack2(f10.x, f10.y); p1.y = pack2(f10.z, f10.w);
      p1.z = pack2(f11.x, f11.y); p1.w = pack2(f11.z, f11.w);
      *(int4*)(wD0 + nbuf * 4096) = p0;
      *(int4*)(wD1 + nbuf * 4096) = p1;
    }
    __syncthreads();
  }

  {  // final tile, no staging
    const int buf = (NT - 1) & 1;
    bf16x8 af[4], bfr[4];
#pragma unroll
    for (int i = 0; i < 4; ++i) {
      af[i]  = *(const bf16x8*)&Al[buf][aRd + i * 512];
      bfr[i] = *(const bf16x8*)&Bl[buf][bRd + i * 512];
    }
#pragma unroll
    for (int i = 0; i < 4; ++i)
#pragma unroll
      for (int j = 0; j < 4; ++j)
        acc[i][j] = __builtin_amdgcn_mfma_f32_16x16x32_bf16(af[i], bfr[j], acc[i][j], 0, 0, 0);
  }

  const int er = (l >> 4) << 2;
  const int ec = l & 15;
#pragma unroll
  for (int i = 0; i < 4; ++i) {
#pragma unroll
    for (int j = 0; j < 4; ++j) {
      int col = n0 + wn + j * 16 + ec;
      if (col >= N) continue;
      float bcol = bias[col];
#pragma unroll
      for (int r = 0; r < 4; ++r) {
        int row = m0 + wm + i * 16 + er + r;
        if (row >= M) continue;
        float v = acc[i][j][r] + bcol;
        size_t off = (size_t)row * N + col;
        if (EPI == 0) {
          Cf[off] = v;
        } else if (EPI == 1) {
          // tanh-GELU (|err| <= ~3e-3, absorbed by bf16 mid)
          float u = v * (0.7978845608f + 0.0356774081f * v * v);
          float e = __expf(2.0f * u);
          float th = 1.0f - 2.0f / (e + 1.0f);
          Cb[off] = f2bf(0.5f * v * (1.0f + th));
        } else if (EPI == 2) {
          Cf[off] = v + R1[off] + R2[off];
        } else if (EPI == 3) {
          Cf[off] += v;
        } else {
          Cb[off] = f2bf(v);
        }
      }
    }
  }
}

// ---------------- softmax + per-point sampling meta: idx0 + 4 bf16 tap wgts
__global__ __launch_bounds__(256) void k_post(const float* __restrict__ res,
                                              const float* __restrict__ refp,
                                              int* __restrict__ idxA,
                                              unsigned short* __restrict__ wA) {
  int t = blockIdx.x * 256 + threadIdx.x;
  if (t >= NQ * 8) return;
  int q = t >> 3, h = t & 7;
  const float* rr = res + (size_t)q * 288;
  const float* lg = rr + 192 + h * 12;
  float mx = lg[0];
#pragma unroll
  for (int i = 1; i < 12; ++i) mx = fmaxf(mx, lg[i]);
  float e[12]; float sum = 0.0f;
#pragma unroll
  for (int i = 0; i < 12; ++i) { e[i] = expf(lg[i] - mx); sum += e[i]; }
  float inv = 1.0f / sum;

  const float dims[3] = {200.0f, 100.0f, 50.0f};
  const int   sts[3]  = {0, 40000, 50000};
#pragma unroll
  for (int l = 0; l < 3; ++l) {
    const int W = (int)dims[l];
    const float fW = dims[l];
    float rx = refp[((size_t)q * 3 + l) * 2 + 0];
    float ry = refp[((size_t)q * 3 + l) * 2 + 1];
    float invd = 1.0f / fW;
#pragma unroll
    for (int p = 0; p < 4; ++p) {
      int j = ((h * 3 + l) * 4 + p) * 2;
      float lx = rx + rr[j + 0] * invd;
      float ly = ry + rr[j + 1] * invd;
      float fx = lx * fW - 0.5f;
      float fy = ly * fW - 0.5f;
      float x0f = floorf(fx), y0f = floorf(fy);
      float tx = fx - x0f, ty = fy - y0f;
      int x0 = (int)x0f, y0 = (int)y0f;
      bool vx0 = (unsigned)x0       < (unsigned)W;
      bool vx1 = (unsigned)(x0 + 1) < (unsigned)W;
      bool vy0 = (unsigned)y0       < (unsigned)W;
      bool vy1 = (unsigned)(y0 + 1) < (unsigned)W;
      float a = e[l * 4 + p] * inv;
      float w00 = (vx0 && vy0) ? a * (1.0f - tx) * (1.0f - ty) : 0.0f;
      float w01 = (vx1 && vy0) ? a * tx * (1.0f - ty) : 0.0f;
      float w10 = (vx0 && vy1) ? a * (1.0f - tx) * ty : 0.0f;
      float w11 = (vx1 && vy1) ? a * tx * ty : 0.0f;
      int pidx = t * 12 + l * 4 + p;
      idxA[pidx] = sts[l] + y0 * W + x0;
      short4 wpk;
      wpk.x = f2bf(w00); wpk.y = f2bf(w01);
      wpk.z = f2bf(w10); wpk.w = f2bf(w11);
      *(short4*)(wA + (size_t)pidx * 4) = wpk;
    }
  }
}

// ----------------------------------------------------------- deform sampling
__global__ __launch_bounds__(256) void k_sample(const short* __restrict__ vproj,
                                                const int* __restrict__ idxA,
                                                const unsigned short* __restrict__ wA,
                                                short* __restrict__ smp) {
  const int lane = threadIdx.x & 63;
  const int qh   = blockIdx.x * 4 + (threadIdx.x >> 6);
  const int h = qh & 7;
  const int pg  = lane >> 4;         // point in level
  const int tap = (lane >> 2) & 3;   // dy,dx
  const int cq  = lane & 3;          // channel oct (8 ch)
  const int dy = tap >> 1, dx = tap & 1;
  const short* vb = vproj + h * HD + cq * 8;

  float acc[8];
#pragma unroll
  for (int j = 0; j < 8; ++j) acc[j] = 0.0f;

  const int Dim[3] = {200, 100, 50};
#pragma unroll
  for (int l = 0; l < 3; ++l) {
    const int W = Dim[l];
    const int tapoff = dy * W + dx;
    int pidx = qh * 12 + l * 4 + pg;
    int idx = idxA[pidx] + tapoff;
    idx = min(max(idx, 0), NV - 1);
    float wgt = __uint_as_float((unsigned)wA[(size_t)pidx * 4 + tap] << 16);
    uint4 v = *(const uint4*)(vb + (size_t)idx * D);
    acc[0] = fmaf(wgt, __uint_as_float(v.x << 16),        acc[0]);
    acc[1] = fmaf(wgt, __uint_as_float(v.x & 0xffff0000u), acc[1]);
    acc[2] = fmaf(wgt, __uint_as_float(v.y << 16),        acc[2]);
    acc[3] = fmaf(wgt, __uint_as_float(v.y & 0xffff0000u), acc[3]);
    acc[4] = fmaf(wgt, __uint_as_float(v.z << 16),        acc[4]);
    acc[5] = fmaf(wgt, __uint_as_float(v.z & 0xffff0000u), acc[5]);
    acc[6] = fmaf(wgt, __uint_as_float(v.w << 16),        acc[6]);
    acc[7] = fmaf(wgt, __uint_as_float(v.w & 0xffff0000u), acc[7]);
  }

#pragma unroll
  for (int off = 4; off <= 32; off <<= 1) {
#pragma unroll
    for (int j = 0; j < 8; ++j) acc[j] += __shfl_xor(acc[j], off);
  }

  if (lane < 4) {
    uint4 o;
    o.x = pack2(acc[0], acc[1]);
    o.y = pack2(acc[2], acc[3]);
    o.z = pack2(acc[4], acc[5]);
    o.w = pack2(acc[6], acc[7]);
    *(uint4*)(smp + (size_t)qh * HD + cq * 8) = o;
  }
}

// ---------------------------------------------------------------------------
extern "C" void kernel_launch(void* const* d_in, const int* in_sizes, int n_in,
                              void* d_out, int out_size, void* d_ws, size_t ws_size,
                              hipStream_t stream) {
  const float* query  = (const float*)d_in[0];
  const float* value  = (const float*)d_in[1];
  const float* qpos   = (const float*)d_in[2];
  const float* refp   = (const float*)d_in[3];
  const float* n1g = (const float*)d_in[6];
  const float* n1b = (const float*)d_in[7];
  const float* Woff = (const float*)d_in[8];
  const float* boff = (const float*)d_in[9];
  const float* Wattn = (const float*)d_in[10];
  const float* battn = (const float*)d_in[11];
  const float* Wval = (const float*)d_in[12];
  const float* bval = (const float*)d_in[13];
  const float* Wout = (const float*)d_in[14];
  const float* bout = (const float*)d_in[15];
  const float* n2g = (const float*)d_in[16];
  const float* n2b = (const float*)d_in[17];
  const float* W1 = (const float*)d_in[18];
  const float* b1 = (const float*)d_in[19];
  const float* W2 = (const float*)d_in[20];
  const float* b2 = (const float*)d_in[21];

  float* out = (float*)d_out;
  char* Wb = (char*)d_ws;

  // workspace layout (time-overlaid; ~156 MB total)
  short* qp_bf   = (short*)Wb;                    // [0,20.48M)   ln1 -> gemm288
  float* iden    = (float*)(Wb + 20480000);       // [20.48M,61.44M) ln1 -> outproj
  int*   idxA    = (int*)(Wb + 61440000);         // [61.44M,76.8M)  post -> sample
  unsigned short* wA = (unsigned short*)(Wb + 76800000); // [76.8M,107.52M)
  float* res     = (float*)(Wb + 107520000);      // [107.52M,153.6M) gemm288 -> post
  short* vprj_bf = (short*)(Wb + 107520000);      // [107.52M,134.4M) vproj -> sample
  short* h_bf    = (short*)(Wb + 107520000);      // [107.52M,128M)   ln2 -> ffn1
  short* smp_bf  = (short*)(Wb + 134400000);      // [134.4M,154.88M) sample -> outproj
  short* mid_bf  = (short*)Wb;                    // [0,81.92M) ffn1 -> ffn2
  short* WT288   = (short*)(Wb + 154880000);
  short* WTval   = (short*)(Wb + 155027456);
  short* WTout   = (short*)(Wb + 155158528);
  short* WT1     = (short*)(Wb + 155289600);
  short* WT2     = (short*)(Wb + 155813888);
  float* bias288 = (float*)(Wb + 156338176);

  // weight prep
  k_wt<<<(192 * 256 + 255) / 256, 256, 0, stream>>>(Woff, WT288, 256, 192);
  k_wt<<<(96 * 256 + 255) / 256, 256, 0, stream>>>(Wattn, WT288 + 192 * 256, 256, 96);
  k_wt<<<(256 * 256 + 255) / 256, 256, 0, stream>>>(Wval, WTval, 256, 256);
  k_wt<<<(256 * 256 + 255) / 256, 256, 0, stream>>>(Wout, WTout, 256, 256);
  k_wt<<<(1024 * 256 + 255) / 256, 256, 0, stream>>>(W1, WT1, 256, 1024);
  k_wt<<<(256 * 1024 + 255) / 256, 256, 0, stream>>>(W2, WT2, 1024, 256);
  k_catbias<<<1, 320, 0, stream>>>(boff, battn, bias288);

  // LN1 -> iden(f32), qp(bf16)
  k_ln1<<<NQ / 4, 256, 0, stream>>>(query, qpos, n1g, n1b, iden, qp_bf);

  // offsets+attn logits GEMM (N=288); grid = (n-tiles, m-tiles)
  k_gemm<0,0,256><<<dim3(3, (NQ + 127) / 128), 256, 0, stream>>>(
      qp_bf, WT288, bias288, res, nullptr, nullptr, nullptr, NQ, 288);
  // softmax + sampling meta
  k_post<<<(NQ * 8 + 255) / 256, 256, 0, stream>>>(res, refp, idxA, wA);

  // value proj (fused f32->bf16 A staging) -> bf16
  k_gemm<4,1,256><<<dim3(2, (NV + 127) / 128), 256, 0, stream>>>(
      value, WTval, bval, nullptr, vprj_bf, nullptr, nullptr, NV, 256);

  // deformable sampling -> smp(bf16)
  k_sample<<<NQ * NHEAD / 4, 256, 0, stream>>>(vprj_bf, idxA, wA, smp_bf);

  // out proj + residuals -> x (d_out)
  k_gemm<2,0,256><<<dim3(2, (NQ + 127) / 128), 256, 0, stream>>>(
      smp_bf, WTout, bout, out, nullptr, query, iden, NQ, 256);

  // LN2 -> h(bf16)
  k_ln2<<<NQ / 4, 256, 0, stream>>>(out, n2g, n2b, h_bf);

  // FFN1: gelu(h@W1+b1) -> mid(bf16)
  k_gemm<1,0,256><<<dim3(8, (NQ + 127) / 128), 256, 0, stream>>>(
      h_bf, WT1, b1, nullptr, mid_bf, nullptr, nullptr, NQ, 1024);

  // FFN2: x += mid@W2+b2 (in place on d_out)
  k_gemm<3,0,1024><<<dim3(2, (NQ + 127) / 128), 256, 0, stream>>>(
      mid_bf, WT2, b2, out, nullptr, nullptr, nullptr, NQ, 256);
}

// Round 8
// 444.096 us; speedup vs baseline: 1.5892x; 1.0838x over previous
//
#include <hip/hip_runtime.h>
#include <hip/hip_bf16.h>
#include <math.h>

#define NQ 40000
#define NV 52500
#define D 256
#define NHEAD 8
#define HD 32
#define GUARD 256   // guard rows around vproj table (clamp-free sampling)

using bf16x8 = __attribute__((ext_vector_type(8))) short;
using f32x4  = __attribute__((ext_vector_type(4))) float;
typedef int v2i32 __attribute__((ext_vector_type(2)));

__device__ __forceinline__ short f2bf(float f) {
  union { __hip_bfloat16 h; short s; } u;
  u.h = __float2bfloat16(f);
  return u.s;
}
__device__ __forceinline__ float bf2f(unsigned short s) {
  return __uint_as_float((unsigned)s << 16);
}
__device__ __forceinline__ unsigned pack2(float lo, float hi) {
  return (unsigned)(unsigned short)f2bf(lo) |
         ((unsigned)(unsigned short)f2bf(hi) << 16);
}
// async global->LDS, 16B per lane, wave-uniform LDS base
__device__ __forceinline__ void gload16(const void* g, void* l) {
  __builtin_amdgcn_global_load_lds(
      (const __attribute__((address_space(1))) unsigned int*)g,
      (__attribute__((address_space(3))) unsigned int*)l, 16, 0, 0);
}

// cross-lane sum helpers: x + x[lane^K]
template<int IMM>
__device__ __forceinline__ float swz_add(float x) {   // K = 4 or 8 (ds pipe)
  return x + __int_as_float(__builtin_amdgcn_ds_swizzle(__float_as_int(x), IMM));
}
__device__ __forceinline__ float xor16_add(float x) {
#if __has_builtin(__builtin_amdgcn_permlane16_swap)
  v2i32 r = __builtin_amdgcn_permlane16_swap(__float_as_int(x), __float_as_int(x), false, false);
  return __int_as_float(r[0]) + __int_as_float(r[1]);
#else
  return x + __shfl_xor(x, 16);
#endif
}
__device__ __forceinline__ float xor32_add(float x) {
#if __has_builtin(__builtin_amdgcn_permlane32_swap)
  v2i32 r = __builtin_amdgcn_permlane32_swap(__float_as_int(x), __float_as_int(x), false, false);
  return __int_as_float(r[0]) + __int_as_float(r[1]);
#else
  return x + __shfl_xor(x, 32);
#endif
}

// ---------------------------------------------------- weight transpose->bf16
__global__ __launch_bounds__(256) void k_wt(const float* __restrict__ Wm,
                                            short* __restrict__ WT, int K, int N) {
  int idx = blockIdx.x * 256 + threadIdx.x;
  if (idx >= N * K) return;
  int n = idx / K, k = idx - n * K;
  WT[idx] = f2bf(Wm[(size_t)k * N + n]);
}

__global__ void k_catbias(const float* __restrict__ a, const float* __restrict__ b,
                          float* __restrict__ o) {
  int i = threadIdx.x;
  if (i < 192) o[i] = a[i];
  else if (i < 288) o[i] = b[i - 192];
}

// ---------------------------------------------------------------- LN1 + qp
__global__ __launch_bounds__(256) void k_ln1(const float* __restrict__ qin,
                                             const float* __restrict__ qpos,
                                             const float* __restrict__ g,
                                             const float* __restrict__ b,
                                             float* __restrict__ id_out,
                                             short* __restrict__ qp_out) {
  int wave = threadIdx.x >> 6;
  int lane = threadIdx.x & 63;
  int row  = blockIdx.x * 4 + wave;
  float4 x = ((const float4*)(qin + (size_t)row * D))[lane];
  float s  = x.x + x.y + x.z + x.w;
  float ss = x.x*x.x + x.y*x.y + x.z*x.z + x.w*x.w;
  for (int o = 32; o > 0; o >>= 1) { s += __shfl_down(s, o); ss += __shfl_down(ss, o); }
  s  = __shfl(s, 0);
  ss = __shfl(ss, 0);
  float m   = s * (1.0f / 256.0f);
  float var = ss * (1.0f / 256.0f) - m * m;
  float rs  = rsqrtf(var + 1e-5f);
  float4 gg = ((const float4*)g)[lane];
  float4 bb = ((const float4*)b)[lane];
  float4 qn;
  qn.x = (x.x - m) * rs * gg.x + bb.x;
  qn.y = (x.y - m) * rs * gg.y + bb.y;
  qn.z = (x.z - m) * rs * gg.z + bb.z;
  qn.w = (x.w - m) * rs * gg.w + bb.w;
  ((float4*)(id_out + (size_t)row * D))[lane] = qn;
  float4 p = ((const float4*)(qpos + (size_t)row * D))[lane];
  short4 o;
  o.x = f2bf(qn.x + p.x); o.y = f2bf(qn.y + p.y);
  o.z = f2bf(qn.z + p.z); o.w = f2bf(qn.w + p.w);
  ((short4*)(qp_out + (size_t)row * D))[lane] = o;
}

// ----------------------------------------------------------- LN2 -> bf16 h
__global__ __launch_bounds__(256) void k_ln2(const float* __restrict__ xin,
                                             const float* __restrict__ g,
                                             const float* __restrict__ b,
                                             short* __restrict__ h_out) {
  int wave = threadIdx.x >> 6;
  int lane = threadIdx.x & 63;
  int row  = blockIdx.x * 4 + wave;
  float4 x = ((const float4*)(xin + (size_t)row * D))[lane];
  float s  = x.x + x.y + x.z + x.w;
  float ss = x.x*x.x + x.y*x.y + x.z*x.z + x.w*x.w;
  for (int o = 32; o > 0; o >>= 1) { s += __shfl_down(s, o); ss += __shfl_down(ss, o); }
  s  = __shfl(s, 0);
  ss = __shfl(ss, 0);
  float m   = s * (1.0f / 256.0f);
  float var = ss * (1.0f / 256.0f) - m * m;
  float rs  = rsqrtf(var + 1e-5f);
  float4 gg = ((const float4*)g)[lane];
  float4 bb = ((const float4*)b)[lane];
  short4 o;
  o.x = f2bf((x.x - m) * rs * gg.x + bb.x);
  o.y = f2bf((x.y - m) * rs * gg.y + bb.y);
  o.z = f2bf((x.z - m) * rs * gg.z + bb.z);
  o.w = f2bf((x.w - m) * rs * gg.w + bb.w);
  ((short4*)(h_out + (size_t)row * D))[lane] = o;
}

// --------------------------------------------------------------- MFMA GEMM
// 128x128 tile, BK=32, double-buffered LDS, 2-phase pipeline, XOR slot
// swizzle (both-sides), XCD-chunked block swizzle for A-tile L2 locality.
// EPI: 0 = store f32; 1 = gelu -> bf16; 2 = + R1 + R2 -> f32; 3 = Cf += v;
//      4 = store bf16
template<int EPI, int CVTA, int K>
__global__ __launch_bounds__(256) void k_gemm(const void* __restrict__ Ain,
                                              const short* __restrict__ WT,
                                              const float* __restrict__ bias,
                                              float* __restrict__ Cf,
                                              short* __restrict__ Cb,
                                              const float* __restrict__ R1,
                                              const float* __restrict__ R2,
                                              int M, int N) {
  constexpr int NT = K / 32;
  __shared__ short Al[2][4096];
  __shared__ short Bl[2][4096];
  const int tid = threadIdx.x;

  // XCD-chunked bijective block swizzle (T1): contiguous flat range per XCD
  const int nbx = gridDim.x;
  const int nwg = nbx * gridDim.y;
  int flat = blockIdx.y * nbx + blockIdx.x;
  {
    int xcd = flat & 7, pos = flat >> 3;
    int qq = nwg >> 3, rr = nwg & 7;
    flat = (xcd < rr ? xcd * (qq + 1) : rr * (qq + 1) + (xcd - rr) * qq) + pos;
  }
  const int n0 = (flat % nbx) * 128, m0 = (flat / nbx) * 128;

  const int w = tid >> 6, l = tid & 63;
  const int wm = (w >> 1) * 64, wn = (w & 1) * 64;
  const int lr = l & 15;

  const int c0 = w * 2, c1 = c0 + 1;
  const int sr = l >> 2;
  const int sg = (((l & 3) ^ ((l >> 3) & 3)) << 3);   // swizzled src slot
  const int ar0 = min(m0 + c0 * 16 + sr, M - 1);
  const int ar1 = min(m0 + c1 * 16 + sr, M - 1);
  const int br0 = min(n0 + c0 * 16 + sr, N - 1);
  const int br1 = min(n0 + c1 * 16 + sr, N - 1);
  const short* bP0 = WT + (size_t)br0 * K + sg;
  const short* bP1 = WT + (size_t)br1 * K + sg;
  const short* aP0 = (const short*)Ain + (size_t)ar0 * K + sg;
  const short* aP1 = (const short*)Ain + (size_t)ar1 * K + sg;
  const float* aF0 = (const float*)Ain + (size_t)ar0 * K + sg;
  const float* aF1 = (const float*)Ain + (size_t)ar1 * K + sg;
  short* wD0 = &Al[0][(c0 * 16 + sr) * 32 + ((l & 3) << 3)];
  short* wD1 = &Al[0][(c1 * 16 + sr) * 32 + ((l & 3) << 3)];

  const int fsw = (((l >> 4) ^ ((l >> 1) & 3)) << 3);  // swizzled read slot
  const int aRd = (wm + lr) * 32 + fsw;
  const int bRd = (wn + lr) * 32 + fsw;

  f32x4 acc[4][4];
#pragma unroll
  for (int i = 0; i < 4; ++i)
#pragma unroll
    for (int j = 0; j < 4; ++j) acc[i][j] = (f32x4){0, 0, 0, 0};

  // ---- prologue: stage tile 0 into buf 0
  if (CVTA) {
    float4 f00 = *(const float4*)(aF0);
    float4 f01 = *(const float4*)(aF0 + 4);
    float4 f10 = *(const float4*)(aF1);
    float4 f11 = *(const float4*)(aF1 + 4);
    int4 p0, p1;
    p0.x = pack2(f00.x, f00.y); p0.y = pack2(f00.z, f00.w);
    p0.z = pack2(f01.x, f01.y); p0.w = pack2(f01.z, f01.w);
    p1.x = pack2(f10.x, f10.y); p1.y = pack2(f10.z, f10.w);
    p1.z = pack2(f11.x, f11.y); p1.w = pack2(f11.z, f11.w);
    *(int4*)wD0 = p0;
    *(int4*)wD1 = p1;
  } else {
    gload16(aP0, &Al[0][c0 * 512]);
    gload16(aP1, &Al[0][c1 * 512]);
  }
  gload16(bP0, &Bl[0][c0 * 512]);
  gload16(bP1, &Bl[0][c1 * 512]);
  __syncthreads();

#pragma unroll 2
  for (int t = 0; t < NT - 1; ++t) {
    const int buf = t & 1, nbuf = buf ^ 1;
    const int kn = (t + 1) * 32;
    float4 f00, f01, f10, f11;
    if (CVTA) {
      f00 = *(const float4*)(aF0 + kn);
      f01 = *(const float4*)(aF0 + kn + 4);
      f10 = *(const float4*)(aF1 + kn);
      f11 = *(const float4*)(aF1 + kn + 4);
    } else {
      gload16(aP0 + kn, &Al[nbuf][c0 * 512]);
      gload16(aP1 + kn, &Al[nbuf][c1 * 512]);
    }
    gload16(bP0 + kn, &Bl[nbuf][c0 * 512]);
    gload16(bP1 + kn, &Bl[nbuf][c1 * 512]);

    bf16x8 af[4], bfr[4];
#pragma unroll
    for (int i = 0; i < 4; ++i) {
      af[i]  = *(const bf16x8*)&Al[buf][aRd + i * 512];
      bfr[i] = *(const bf16x8*)&Bl[buf][bRd + i * 512];
    }
#pragma unroll
    for (int i = 0; i < 4; ++i)
#pragma unroll
      for (int j = 0; j < 4; ++j)
        acc[i][j] = __builtin_amdgcn_mfma_f32_16x16x32_bf16(af[i], bfr[j], acc[i][j], 0, 0, 0);

    if (CVTA) {
      int4 p0, p1;
      p0.x = pack2(f00.x, f00.y); p0.y = pack2(f00.z, f00.w);
      p0.z = pack2(f01.x, f01.y); p0.w = pack2(f01.z, f01.w);
      p1.x = pack2(f10.x, f10.y); p1.y = pack2(f10.z, f10.w);
      p1.z = pack2(f11.x, f11.y); p1.w = pack2(f11.z, f11.w);
      *(int4*)(wD0 + nbuf * 4096) = p0;
      *(int4*)(wD1 + nbuf * 4096) = p1;
    }
    __syncthreads();
  }

  {  // final tile
    const int buf = (NT - 1) & 1;
    bf16x8 af[4], bfr[4];
#pragma unroll
    for (int i = 0; i < 4; ++i) {
      af[i]  = *(const bf16x8*)&Al[buf][aRd + i * 512];
      bfr[i] = *(const bf16x8*)&Bl[buf][bRd + i * 512];
    }
#pragma unroll
    for (int i = 0; i < 4; ++i)
#pragma unroll
      for (int j = 0; j < 4; ++j)
        acc[i][j] = __builtin_amdgcn_mfma_f32_16x16x32_bf16(af[i], bfr[j], acc[i][j], 0, 0, 0);
  }

  const int er = (l >> 4) << 2;
  const int ec = l & 15;
#pragma unroll
  for (int i = 0; i < 4; ++i) {
#pragma unroll
    for (int j = 0; j < 4; ++j) {
      int col = n0 + wn + j * 16 + ec;
      if (col >= N) continue;
      float bcol = bias[col];
#pragma unroll
      for (int r = 0; r < 4; ++r) {
        int row = m0 + wm + i * 16 + er + r;
        if (row >= M) continue;
        float v = acc[i][j][r] + bcol;
        size_t off = (size_t)row * N + col;
        if (EPI == 0) {
          Cf[off] = v;
        } else if (EPI == 1) {
          float u = v * (0.7978845608f + 0.0356774081f * v * v);
          float e = __expf(2.0f * u);
          float th = 1.0f - 2.0f / (e + 1.0f);
          Cb[off] = f2bf(0.5f * v * (1.0f + th));
        } else if (EPI == 2) {
          Cf[off] = v + R1[off] + R2[off];
        } else if (EPI == 3) {
          Cf[off] += v;
        } else {
          Cb[off] = f2bf(v);
        }
      }
    }
  }
}

// -------- softmax + per-point sampling meta (reads bf16 res): idx0 + 4 wgts
__global__ __launch_bounds__(256) void k_post(const unsigned short* __restrict__ res,
                                              const float* __restrict__ refp,
                                              int* __restrict__ idxA,
                                              unsigned short* __restrict__ wA) {
  int t = blockIdx.x * 256 + threadIdx.x;
  if (t >= NQ * 8) return;
  int q = t >> 3, h = t & 7;
  const unsigned short* rr = res + (size_t)q * 288;
  const unsigned short* lg = rr + 192 + h * 12;
  float lf[12];
#pragma unroll
  for (int i = 0; i < 12; ++i) lf[i] = bf2f(lg[i]);
  float mx = lf[0];
#pragma unroll
  for (int i = 1; i < 12; ++i) mx = fmaxf(mx, lf[i]);
  float e[12]; float sum = 0.0f;
#pragma unroll
  for (int i = 0; i < 12; ++i) { e[i] = expf(lf[i] - mx); sum += e[i]; }
  float inv = 1.0f / sum;

  const float dims[3] = {200.0f, 100.0f, 50.0f};
  const int   sts[3]  = {0, 40000, 50000};
#pragma unroll
  for (int l = 0; l < 3; ++l) {
    const int W = (int)dims[l];
    const float fW = dims[l];
    float rx = refp[((size_t)q * 3 + l) * 2 + 0];
    float ry = refp[((size_t)q * 3 + l) * 2 + 1];
    float invd = 1.0f / fW;
#pragma unroll
    for (int p = 0; p < 4; ++p) {
      int j = ((h * 3 + l) * 4 + p) * 2;
      float lx = rx + bf2f(rr[j + 0]) * invd;
      float ly = ry + bf2f(rr[j + 1]) * invd;
      float fx = lx * fW - 0.5f;
      float fy = ly * fW - 0.5f;
      float x0f = floorf(fx), y0f = floorf(fy);
      float tx = fx - x0f, ty = fy - y0f;
      int x0 = (int)x0f, y0 = (int)y0f;
      bool vx0 = (unsigned)x0       < (unsigned)W;
      bool vx1 = (unsigned)(x0 + 1) < (unsigned)W;
      bool vy0 = (unsigned)y0       < (unsigned)W;
      bool vy1 = (unsigned)(y0 + 1) < (unsigned)W;
      float a = e[l * 4 + p] * inv;
      float w00 = (vx0 && vy0) ? a * (1.0f - tx) * (1.0f - ty) : 0.0f;
      float w01 = (vx1 && vy0) ? a * tx * (1.0f - ty) : 0.0f;
      float w10 = (vx0 && vy1) ? a * (1.0f - tx) * ty : 0.0f;
      float w11 = (vx1 && vy1) ? a * tx * ty : 0.0f;
      int pidx = t * 12 + l * 4 + p;
      idxA[pidx] = sts[l] + y0 * W + x0;
      short4 wpk;
      wpk.x = f2bf(w00); wpk.y = f2bf(w01);
      wpk.z = f2bf(w10); wpk.w = f2bf(w11);
      *(short4*)(wA + (size_t)pidx * 4) = wpk;
    }
  }
}

// ----------------------------------------------------------- deform sampling
// vprojG points to guard region start; table begins at +GUARD rows.
// No clamp: OOB taps carry weight 0 and land in the (finite-garbage) guard.
__global__ __launch_bounds__(256) void k_sample(const short* __restrict__ vprojG,
                                                const int* __restrict__ idxA,
                                                const unsigned short* __restrict__ wA,
                                                short* __restrict__ smp) {
  const int lane = threadIdx.x & 63;
  const int qh   = blockIdx.x * 4 + (threadIdx.x >> 6);
  const int h = qh & 7;
  const int pg  = lane >> 4;         // point in level
  const int tap = (lane >> 2) & 3;   // dy,dx
  const int cq  = lane & 3;          // channel oct (8 ch)
  const int dy = tap >> 1, dx = tap & 1;
  const short* vb = vprojG + (size_t)GUARD * D + h * HD + cq * 8;

  float acc[8];
#pragma unroll
  for (int j = 0; j < 8; ++j) acc[j] = 0.0f;

  const int Dim[3] = {200, 100, 50};
#pragma unroll
  for (int l = 0; l < 3; ++l) {
    const int W = Dim[l];
    const int tapoff = dy * W + dx;
    int pidx = qh * 12 + l * 4 + pg;
    int idx = idxA[pidx] + tapoff;
    float wgt = __uint_as_float((unsigned)wA[(size_t)pidx * 4 + tap] << 16);
    uint4 v = *(const uint4*)(vb + (ptrdiff_t)idx * D);
    acc[0] = fmaf(wgt, __uint_as_float(v.x << 16),        acc[0]);
    acc[1] = fmaf(wgt, __uint_as_float(v.x & 0xffff0000u), acc[1]);
    acc[2] = fmaf(wgt, __uint_as_float(v.y << 16),        acc[2]);
    acc[3] = fmaf(wgt, __uint_as_float(v.y & 0xffff0000u), acc[3]);
    acc[4] = fmaf(wgt, __uint_as_float(v.z << 16),        acc[4]);
    acc[5] = fmaf(wgt, __uint_as_float(v.z & 0xffff0000u), acc[5]);
    acc[6] = fmaf(wgt, __uint_as_float(v.w << 16),        acc[6]);
    acc[7] = fmaf(wgt, __uint_as_float(v.w & 0xffff0000u), acc[7]);
  }

  // reduce taps (lane bits 2,3: ds_swizzle) and points (bits 4,5: permlane)
#pragma unroll
  for (int j = 0; j < 8; ++j) {
    float a = swz_add<0x101F>(acc[j]);   // ^4
    a = swz_add<0x201F>(a);              // ^8
    a = xor16_add(a);                    // ^16
    acc[j] = xor32_add(a);               // ^32
  }

  if (lane < 4) {
    uint4 o;
    o.x = pack2(acc[0], acc[1]);
    o.y = pack2(acc[2], acc[3]);
    o.z = pack2(acc[4], acc[5]);
    o.w = pack2(acc[6], acc[7]);
    *(uint4*)(smp + (size_t)qh * HD + cq * 8) = o;
  }
}

// ---------------------------------------------------------------------------
extern "C" void kernel_launch(void* const* d_in, const int* in_sizes, int n_in,
                              void* d_out, int out_size, void* d_ws, size_t ws_size,
                              hipStream_t stream) {
  const float* query  = (const float*)d_in[0];
  const float* value  = (const float*)d_in[1];
  const float* qpos   = (const float*)d_in[2];
  const float* refp   = (const float*)d_in[3];
  const float* n1g = (const float*)d_in[6];
  const float* n1b = (const float*)d_in[7];
  const float* Woff = (const float*)d_in[8];
  const float* boff = (const float*)d_in[9];
  const float* Wattn = (const float*)d_in[10];
  const float* battn = (const float*)d_in[11];
  const float* Wval = (const float*)d_in[12];
  const float* bval = (const float*)d_in[13];
  const float* Wout = (const float*)d_in[14];
  const float* bout = (const float*)d_in[15];
  const float* n2g = (const float*)d_in[16];
  const float* n2b = (const float*)d_in[17];
  const float* W1 = (const float*)d_in[18];
  const float* b1 = (const float*)d_in[19];
  const float* W2 = (const float*)d_in[20];
  const float* b2 = (const float*)d_in[21];

  float* out = (float*)d_out;
  char* Wb = (char*)d_ws;

  // workspace layout (time-overlaid; ~156.6 MB total)
  short* qp_bf   = (short*)Wb;                    // [0,20.48M)   ln1 -> gemm288
  float* iden    = (float*)(Wb + 20480000);       // [20.48M,61.44M) ln1 -> outproj
  int*   idxA    = (int*)(Wb + 61440000);         // [61.44M,76.8M)  post -> sample
  unsigned short* wA = (unsigned short*)(Wb + 76800000); // [76.8M,107.52M)
  short* res_bf  = (short*)(Wb + 107520000);      // 23.04MB  gemm288 -> post
  short* vprjG   = (short*)(Wb + 107520000);      // guard+26.88MB+guard -> sample
  short* vprj_bf = (short*)(Wb + 107520000 + GUARD * D * 2); // table start
  short* h_bf    = (short*)(Wb + 107520000);      // 20.48MB  ln2 -> ffn1
  short* smp_bf  = (short*)(Wb + 134662144);      // 20.48MB  sample -> outproj
  short* mid_bf  = (short*)Wb;                    // [0,81.92M) ffn1 -> ffn2
  char*  Wbase   = Wb + 155142144;
  short* WT288   = (short*)(Wbase);
  short* WTval   = (short*)(Wbase + 147456);
  short* WTout   = (short*)(Wbase + 278528);
  short* WT1     = (short*)(Wbase + 409600);
  short* WT2     = (short*)(Wbase + 933888);
  float* bias288 = (float*)(Wbase + 1458176);

  // weight prep
  k_wt<<<(192 * 256 + 255) / 256, 256, 0, stream>>>(Woff, WT288, 256, 192);
  k_wt<<<(96 * 256 + 255) / 256, 256, 0, stream>>>(Wattn, WT288 + 192 * 256, 256, 96);
  k_wt<<<(256 * 256 + 255) / 256, 256, 0, stream>>>(Wval, WTval, 256, 256);
  k_wt<<<(256 * 256 + 255) / 256, 256, 0, stream>>>(Wout, WTout, 256, 256);
  k_wt<<<(1024 * 256 + 255) / 256, 256, 0, stream>>>(W1, WT1, 256, 1024);
  k_wt<<<(256 * 1024 + 255) / 256, 256, 0, stream>>>(W2, WT2, 1024, 256);
  k_catbias<<<1, 320, 0, stream>>>(boff, battn, bias288);

  // LN1 -> iden(f32), qp(bf16)
  k_ln1<<<NQ / 4, 256, 0, stream>>>(query, qpos, n1g, n1b, iden, qp_bf);

  // offsets+attn logits GEMM (N=288) -> bf16 res
  k_gemm<4,0,256><<<dim3(3, (NQ + 127) / 128), 256, 0, stream>>>(
      qp_bf, WT288, bias288, nullptr, res_bf, nullptr, nullptr, NQ, 288);
  // softmax + sampling meta
  k_post<<<(NQ * 8 + 255) / 256, 256, 0, stream>>>(
      (const unsigned short*)res_bf, refp, idxA, wA);

  // value proj (fused f32->bf16 A staging) -> bf16 (guard-padded table)
  k_gemm<4,1,256><<<dim3(2, (NV + 127) / 128), 256, 0, stream>>>(
      value, WTval, bval, nullptr, vprj_bf, nullptr, nullptr, NV, 256);

  // deformable sampling -> smp(bf16)
  k_sample<<<NQ * NHEAD / 4, 256, 0, stream>>>(vprjG, idxA, wA, smp_bf);

  // out proj + residuals -> x (d_out)
  k_gemm<2,0,256><<<dim3(2, (NQ + 127) / 128), 256, 0, stream>>>(
      smp_bf, WTout, bout, out, nullptr, query, iden, NQ, 256);

  // LN2 -> h(bf16)
  k_ln2<<<NQ / 4, 256, 0, stream>>>(out, n2g, n2b, h_bf);

  // FFN1: gelu(h@W1+b1) -> mid(bf16)
  k_gemm<1,0,256><<<dim3(8, (NQ + 127) / 128), 256, 0, stream>>>(
      h_bf, WT1, b1, nullptr, mid_bf, nullptr, nullptr, NQ, 1024);

  // FFN2: x += mid@W2+b2 (in place on d_out)
  k_gemm<3,0,1024><<<dim3(2, (NQ + 127) / 128), 256, 0, stream>>>(
      mid_bf, WT2, b2, out, nullptr, nullptr, nullptr, NQ, 256);
}